// Round 2
// baseline (287.187 us; speedup 1.0000x reference)
//
#include <hip/hip_runtime.h>
#include <hip/hip_bf16.h>

#define NN 100000
#define NE 1600000
#define NF 128
#define NH 64
#define NC 16
#define NB1 391    // ceil(NN/256)
#define GBIN 256   // binning workgroups
#define CHUNK 6250 // NE/GBIN
#define BBUK 196   // ceil(NN/512) coarse buckets of 512 nodes
#define NCB 196    // 256-blocks per counts array (BBUK*GBIN/256)
#define NGRP 1563  // ceil(NN/64) gemm1 row-groups
#define NHALF 50000 // NN/2 for two-row interleaved aggregation

typedef __attribute__((ext_vector_type(8))) short short8v;
typedef __attribute__((ext_vector_type(4))) float float4v;

__device__ __forceinline__ float us2f(unsigned short u) {
    return __uint_as_float(((unsigned int)u) << 16);
}
__device__ __forceinline__ float bflo(unsigned u) {   // low bf16 of a packed pair
    return __uint_as_float(u << 16);
}
__device__ __forceinline__ float bfhi(unsigned u) {   // high bf16 of a packed pair
    return __uint_as_float(u & 0xFFFF0000u);
}
__device__ __forceinline__ unsigned short f2us_rn(float f) {
    unsigned int u = __float_as_uint(f);
    return (unsigned short)((u + 0x7FFFu + ((u >> 16) & 1u)) >> 16);
}
__device__ __forceinline__ float ldf(const void* p, size_t i, bool f32) {
    return f32 ? ((const float*)p)[i] : us2f(((const unsigned short*)p)[i]);
}

// ---------------- dtype sniff (validated R2; live mode=1/fp32 per R9) ----------------
__global__ void k_sniff(const unsigned short* __restrict__ xu, int* __restrict__ mode) {
    __shared__ int cnt;
    if (threadIdx.x == 0) cnt = 0;
    __syncthreads();
    int c = 0;
    for (int i = threadIdx.x; i < 4096; i += 256) {
        unsigned int e = (xu[i] >> 7) & 0xFFu;
        if (e >= 160u) c++;
    }
    atomicAdd(&cnt, c);
    __syncthreads();
    if (threadIdx.x == 0) mode[0] = (cnt >= 16) ? 1 : 0;
}

// ---------------- fallback path kernels (global atomics) ----------------
__global__ void k_deg(const int4* __restrict__ src4, const int4* __restrict__ dst4,
                      int* __restrict__ deg_out, int* __restrict__ deg_in) {
    int i = blockIdx.x * blockDim.x + threadIdx.x;
    if (i < NE / 4) {
        int4 s = src4[i], d = dst4[i];
        atomicAdd(&deg_out[s.x], 1); atomicAdd(&deg_out[s.y], 1);
        atomicAdd(&deg_out[s.z], 1); atomicAdd(&deg_out[s.w], 1);
        atomicAdd(&deg_in[d.x], 1);  atomicAdd(&deg_in[d.y], 1);
        atomicAdd(&deg_in[d.z], 1);  atomicAdd(&deg_in[d.w], 1);
    }
}

__global__ void k_scatter(const int* __restrict__ src, const int* __restrict__ dst,
                          int* __restrict__ cursor, int* __restrict__ srcs_sorted) {
    int e = blockIdx.x * blockDim.x + threadIdx.x;
    if (e < NE) {
        int p = atomicAdd(&cursor[dst[e]], 1);
        srcs_sorted[p] = src[e];
    }
}

__global__ void k_scan_a(const int* __restrict__ deg_in, int* __restrict__ bsum) {
    __shared__ int s[256];
    int i = blockIdx.x * 256 + threadIdx.x;
    s[threadIdx.x] = (i < NN) ? deg_in[i] : 0;
    __syncthreads();
    for (int off = 128; off > 0; off >>= 1) {
        if (threadIdx.x < off) s[threadIdx.x] += s[threadIdx.x + off];
        __syncthreads();
    }
    if (threadIdx.x == 0) bsum[blockIdx.x] = s[0];
}

__global__ void k_scan_b(const int* __restrict__ bsum, int* __restrict__ boff) {
    __shared__ int s[512];
    int t = threadIdx.x;
    s[t] = (t < NB1) ? bsum[t] : 0;
    __syncthreads();
    for (int off = 1; off < 512; off <<= 1) {
        int v = (t >= off) ? s[t - off] : 0;
        __syncthreads();
        s[t] += v;
        __syncthreads();
    }
    if (t < NB1) boff[t] = (t == 0) ? 0 : s[t - 1];
}

__global__ void k_scan_c(const int* __restrict__ deg_in, const int* __restrict__ deg_out,
                         const int* __restrict__ boff, int* __restrict__ row_off,
                         int* __restrict__ cursor, float* __restrict__ nsrc,
                         float* __restrict__ ndst) {
    __shared__ int s[256];
    int t = threadIdx.x;
    int i = blockIdx.x * 256 + t;
    int d = (i < NN) ? deg_in[i] : 0;
    s[t] = d;
    __syncthreads();
    for (int off = 1; off < 256; off <<= 1) {
        int v = (t >= off) ? s[t - off] : 0;
        __syncthreads();
        s[t] += v;
        __syncthreads();
    }
    int excl = s[t] - d + boff[blockIdx.x];
    if (i < NN) {
        row_off[i] = excl;
        cursor[i]  = excl;
        ndst[i] = rsqrtf(fmaxf((float)d, 1.0f));
        nsrc[i] = rsqrtf(fmaxf((float)deg_out[i], 1.0f));
        if (i == NN - 1) row_off[NN] = excl + d;
    }
}

// ---------------- fast CSR 1: per-(bucket,group) histograms of dst AND src ----------------
__global__ __launch_bounds__(256) void k_hist2(const int* __restrict__ src,
                                               const int* __restrict__ dst,
                                               int* __restrict__ counts_d,
                                               int* __restrict__ counts_s) {
    __shared__ int hd[BBUK], hs[BBUK];
    for (int i = threadIdx.x; i < BBUK; i += 256) { hd[i] = 0; hs[i] = 0; }
    __syncthreads();
    const int g = blockIdx.x;
    const int e0 = g * CHUNK;
    for (int i = threadIdx.x; i < CHUNK; i += 256) {
        atomicAdd(&hd[dst[e0 + i] >> 9], 1);
        atomicAdd(&hs[src[e0 + i] >> 9], 1);
    }
    __syncthreads();
    for (int i = threadIdx.x; i < BBUK; i += 256) {
        counts_d[i * GBIN + g] = hd[i];
        counts_s[i * GBIN + g] = hs[i];
    }
}

// ---------------- fast CSR 2: fused exclusive scan of both counts arrays ----------------
__global__ void k_cs_a(const int* __restrict__ counts, int* __restrict__ csum) {
    __shared__ int s[256];
    int i = blockIdx.x * 256 + threadIdx.x;
    s[threadIdx.x] = counts[i];
    __syncthreads();
    for (int off = 128; off > 0; off >>= 1) {
        if (threadIdx.x < off) s[threadIdx.x] += s[threadIdx.x + off];
        __syncthreads();
    }
    if (threadIdx.x == 0) csum[blockIdx.x] = s[0];
}

__global__ void k_cs_b2(const int* __restrict__ csum, int* __restrict__ coff) {
    __shared__ int s[512];
    int t = threadIdx.x;
    int half = t >> 8, j = t & 255;
    s[t] = (j < NCB) ? csum[half * NCB + j] : 0;
    __syncthreads();
    for (int off = 1; off < 256; off <<= 1) {
        int v = (j >= off) ? s[t - off] : 0;
        __syncthreads();
        s[t] += v;
        __syncthreads();
    }
    if (j < NCB) coff[half * NCB + j] = (j == 0) ? 0 : s[t - 1];
}

__global__ void k_cs_c(int* __restrict__ counts, const int* __restrict__ coff) {
    __shared__ int s[256];
    int t = threadIdx.x;
    int i = blockIdx.x * 256 + t;
    int v = counts[i];
    s[t] = v;
    __syncthreads();
    for (int off = 1; off < 256; off <<= 1) {
        int u = (t >= off) ? s[t - off] : 0;
        __syncthreads();
        s[t] += u;
        __syncthreads();
    }
    counts[i] = s[t] - v + coff[blockIdx.x];
}

// ---------------- fast CSR 3: private-slice binning of dst-edges AND src-residues ----------------
__global__ __launch_bounds__(256) void k_binscatter2(const int* __restrict__ src,
                                                     const int* __restrict__ dst,
                                                     const int* __restrict__ counts_d,
                                                     const int* __restrict__ counts_s,
                                                     unsigned int* __restrict__ packed,
                                                     unsigned short* __restrict__ packed2) {
    __shared__ int curd[BBUK], curs[BBUK];
    const int g = blockIdx.x;
    for (int i = threadIdx.x; i < BBUK; i += 256) {
        curd[i] = counts_d[i * GBIN + g];
        curs[i] = counts_s[i * GBIN + g];
    }
    __syncthreads();
    const int e0 = g * CHUNK;
    for (int i = threadIdx.x; i < CHUNK; i += 256) {
        int s = src[e0 + i], d = dst[e0 + i];
        int pd = atomicAdd(&curd[d >> 9], 1);
        packed[pd] = ((unsigned)s << 9) | (unsigned)(d & 511);
        int ps = atomicAdd(&curs[s >> 9], 1);
        packed2[ps] = (unsigned short)(s & 511);
    }
}

// ---------------- fast CSR 4: per-bucket out-degree histogram -> nsrc directly ----------------
__global__ __launch_bounds__(256) void k_bdeg_out_nsrc(const int* __restrict__ counts_s,
                                                       const unsigned short* __restrict__ packed2,
                                                       float* __restrict__ nsrc) {
    __shared__ int h[512];
    const int b = blockIdx.x;
    const int n0 = b << 9;
    const int nlim = (NN - n0 < 512) ? (NN - n0) : 512;
    for (int j = threadIdx.x; j < 512; j += 256) h[j] = 0;
    __syncthreads();
    const int beg = counts_s[b * GBIN];
    const int end = (b + 1 < BBUK) ? counts_s[(b + 1) * GBIN] : NE;
    for (int i = beg + threadIdx.x; i < end; i += 256)
        atomicAdd(&h[packed2[i] & 511u], 1);
    __syncthreads();
    for (int j = threadIdx.x; j < nlim; j += 256)
        nsrc[n0 + j] = rsqrtf(fmaxf((float)h[j], 1.0f));
}

// ---------------- fast CSR 5 (fused): in-deg histogram + intra-bucket Blelloch scan
//                  + row_off/ndst write + within-bucket scatter, one kernel ----------------
__global__ __launch_bounds__(256) void k_bucket_all(const int* __restrict__ counts_d,
                                                    const unsigned int* __restrict__ packed,
                                                    int* __restrict__ row_off,
                                                    float* __restrict__ ndst,
                                                    int* __restrict__ srcs_sorted) {
    __shared__ int h[512];
    const int b = blockIdx.x;
    const int n0 = b << 9;
    const int nlim = (NN - n0 < 512) ? (NN - n0) : 512;
    const int t = threadIdx.x;
    for (int j = t; j < 512; j += 256) h[j] = 0;
    __syncthreads();
    const int beg = counts_d[b * GBIN];
    const int end = (b + 1 < BBUK) ? counts_d[(b + 1) * GBIN] : NE;
    // 1) in-degree histogram over this bucket's packed slice
    for (int i = beg + t; i < end; i += 256)
        atomicAdd(&h[packed[i] & 511u], 1);
    __syncthreads();
    const int degA = h[t], degB = h[t + 256];   // saved for ndst
    // 2) Blelloch exclusive scan of 512 elems (256 threads)
    int offset = 1;
    #pragma unroll
    for (int d = 256; d > 0; d >>= 1) {
        __syncthreads();
        if (t < d) {
            int ai = offset * (2 * t + 1) - 1;
            int bi = offset * (2 * t + 2) - 1;
            h[bi] += h[ai];
        }
        offset <<= 1;
    }
    __syncthreads();
    if (t == 0) h[511] = 0;
    #pragma unroll
    for (int d = 1; d < 512; d <<= 1) {
        offset >>= 1;
        __syncthreads();
        if (t < d) {
            int ai = offset * (2 * t + 1) - 1;
            int bi = offset * (2 * t + 2) - 1;
            int tmp = h[ai]; h[ai] = h[bi]; h[bi] += tmp;
        }
    }
    __syncthreads();
    // 3) row_off / ndst / cursor init
    const int r0 = beg + h[t];
    const int r1 = beg + h[t + 256];
    if (t < nlim) {
        row_off[n0 + t] = r0;
        ndst[n0 + t] = rsqrtf(fmaxf((float)degA, 1.0f));
    }
    if (t + 256 < nlim) {
        row_off[n0 + t + 256] = r1;
        ndst[n0 + t + 256] = rsqrtf(fmaxf((float)degB, 1.0f));
    }
    if (n0 + nlim == NN && t == 0) row_off[NN] = end;
    __syncthreads();
    h[t] = r0; h[t + 256] = r1;   // LDS cursors
    __syncthreads();
    // 4) within-bucket scatter (re-read is L2-hot)
    for (int i = beg + t; i < end; i += 256) {
        unsigned v = packed[i];
        int p = atomicAdd(&h[v & 511u], 1);
        srcs_sorted[p] = (int)(v >> 9);
    }
}

// ---------------- W1 -> bf16 fragment-ordered layout ----------------
__global__ void k_prepW(const void* __restrict__ W1, unsigned short* __restrict__ W1f,
                        const int* __restrict__ mode) {
    const bool f32 = (mode[0] != 0);
    for (int i = threadIdx.x; i < 1024; i += 256) {
        const int kcnt = i >> 6, lane = i & 63;
        const int kc = kcnt >> 2, nt = kcnt & 3;
        const int quad = lane >> 4, col = lane & 15;
        #pragma unroll
        for (int j = 0; j < 8; ++j) {
            const size_t idx = (size_t)(kc * 32 + quad * 8 + j) * NH + nt * 16 + col;
            W1f[(size_t)i * 8 + j] = f32 ? f2us_rn(((const float*)W1)[idx])
                                         : ((const unsigned short*)W1)[idx];
        }
    }
}

// ---------------- layer 1 GEMM (MFMA, both dtypes) ----------------
__global__ __launch_bounds__(256) void k_gemm1_mfma(
    const void* __restrict__ x, const unsigned short* __restrict__ W1f,
    const float* __restrict__ nsrc, unsigned short* __restrict__ h1,
    const int* __restrict__ mode)
{
    const bool f32 = (mode[0] != 0);
    const int tid = threadIdx.x;
    const int wave = tid >> 6, lane = tid & 63;
    const int col = lane & 15, quad = lane >> 4;

    short8v bfrag[16];
    #pragma unroll
    for (int f = 0; f < 16; ++f)
        bfrag[f] = *(const short8v*)(W1f + ((size_t)f * 64 + lane) * 8);

    const int base = blockIdx.x * 64 + wave * 16;
    int arow = base + col;
    if (arow > NN - 1) arow = NN - 1;

    short8v afrag[4];
    if (f32) {
        const float4* ap = (const float4*)((const float*)x + (size_t)arow * NF);
        #pragma unroll
        for (int kc = 0; kc < 4; ++kc) {
            float4 v0 = ap[kc * 8 + quad * 2];
            float4 v1 = ap[kc * 8 + quad * 2 + 1];
            short8v af;
            af[0] = (short)f2us_rn(v0.x); af[1] = (short)f2us_rn(v0.y);
            af[2] = (short)f2us_rn(v0.z); af[3] = (short)f2us_rn(v0.w);
            af[4] = (short)f2us_rn(v1.x); af[5] = (short)f2us_rn(v1.y);
            af[6] = (short)f2us_rn(v1.z); af[7] = (short)f2us_rn(v1.w);
            afrag[kc] = af;
        }
    } else {
        const uint4* ap = (const uint4*)((const unsigned short*)x + (size_t)arow * NF);
        #pragma unroll
        for (int kc = 0; kc < 4; ++kc) {
            uint4 v = ap[kc * 4 + quad];
            afrag[kc] = *reinterpret_cast<const short8v*>(&v);
        }
    }

    float4v acc[4];
    #pragma unroll
    for (int nt = 0; nt < 4; ++nt) acc[nt] = (float4v){0.f, 0.f, 0.f, 0.f};
    #pragma unroll
    for (int kc = 0; kc < 4; ++kc)
        #pragma unroll
        for (int nt = 0; nt < 4; ++nt)
            acc[nt] = __builtin_amdgcn_mfma_f32_16x16x32_bf16(afrag[kc], bfrag[kc * 4 + nt], acc[nt], 0, 0, 0);

    #pragma unroll
    for (int reg = 0; reg < 4; ++reg) {
        const int row = base + quad * 4 + reg;
        if (row < NN) {
            const float ns = nsrc[row];
            unsigned short* hp = h1 + (size_t)row * NH + col;
            hp[0]  = f2us_rn(acc[0][reg] * ns);
            hp[16] = f2us_rn(acc[1][reg] * ns);
            hp[32] = f2us_rn(acc[2][reg] * ns);
            hp[48] = f2us_rn(acc[3][reg] * ns);
        }
    }
}

// ---------------- fused layer-1 aggregation + relu + W2 GEMM ----------------
// R10: 4 slots x 16 feature-quads, dwordx2, 2-deep (60.6 us).
// R11: 8-slot/dwordx4 variant 70.3 us - REVERTED.
// R12: 4-deep pipeline + 32-bit addressing: VALUBusy 41->38.5% at SAME 60us ->
//      proof the kernel is stall-dominated, not issue-limited. VGPR=32 was the
//      giveaway: only ~8 loads in flight per wave, duty cycle ~10%, 5.6 waves/
//      SIMD -> ~55% issue coverage.
// R13: TWO-ROW INTERLEAVE. Each wave processes rowA in [0,NHALF) and
//      rowB = rowA+NHALF concurrently: 8 srcs loads + 8 gathers in flight,
//      epilogue shuffles interleaved. Doubles per-wave MLP at the cost of
//      VGPR 32->~80 (still ~6 waves/SIMD at 512-reg budget).
__global__ __launch_bounds__(256) void k_agg1csr(
    const int* __restrict__ row_off, const int* __restrict__ srcs,
    const unsigned short* __restrict__ h1, const float* __restrict__ ndst,
    const float* __restrict__ nsrc, const void* __restrict__ b1,
    const void* __restrict__ W2, const int* __restrict__ mode,
    unsigned short* __restrict__ h2)
{
    const bool f32 = (mode[0] != 0);
    const int lane = threadIdx.x & 63;
    const int q  = lane >> 4;    // edge slot / column subset
    const int li = lane & 15;    // feature quad: feats 4li..4li+3

    const float bias0 = ldf(b1, 4*li+0, f32), bias1 = ldf(b1, 4*li+1, f32);
    const float bias2 = ldf(b1, 4*li+2, f32), bias3 = ldf(b1, 4*li+3, f32);
    float w2[4][4];
    #pragma unroll
    for (int j = 0; j < 4; ++j)
        #pragma unroll
        for (int m = 0; m < 4; ++m)
            w2[j][m] = ldf(W2, (size_t)(4*li+j)*NC + (q + 4*m), f32);

    const int wid = (blockIdx.x * blockDim.x + threadIdx.x) >> 6;
    const int nw  = (gridDim.x * blockDim.x) >> 6;
    const uint2* __restrict__ h1v = (const uint2*)h1;
    const unsigned uli = (unsigned)li;

    int rA = wid;
    if (rA >= NHALF) return;
    int begA = row_off[rA],        endA = row_off[rA + 1];
    int begB = row_off[rA + NHALF], endB = row_off[rA + NHALF + 1];
    float ndA = ndst[rA],         nsA = nsrc[rA];
    float ndB = ndst[rA + NHALF], nsB = nsrc[rA + NHALF];

    while (rA < NHALF) {
        const int rB = rA + NHALF;
        // prefetch next pair's descriptors; in flight during this pair's gathers
        const int nrA = rA + nw;
        int nbegA = 0, nendA = 0, nbegB = 0, nendB = 0;
        float nndA = 0.f, nnsA = 0.f, nndB = 0.f, nnsB = 0.f;
        if (nrA < NHALF) {
            nbegA = row_off[nrA];          nendA = row_off[nrA + 1];
            nbegB = row_off[nrA + NHALF];  nendB = row_off[nrA + NHALF + 1];
            nndA  = ndst[nrA];             nnsA  = nsrc[nrA];
            nndB  = ndst[nrA + NHALF];     nnsB  = nsrc[nrA + NHALF];
        }

        float aA0 = 0.f, aA1 = 0.f, aA2 = 0.f, aA3 = 0.f;
        float aB0 = 0.f, aB1 = 0.f, aB2 = 0.f, aB3 = 0.f;
        const int eA1 = endA - 1, eB1 = endB - 1;
        int iA = begA + q, iB = begB + q;
        bool mA = iA < endA, mB = iB < endB;     // wave-uniform in practice
        while (mA || mB) {
            int sA0, sA1, sA2, sA3, sB0, sB1, sB2, sB3;
            uint2 vA0, vA1, vA2, vA3, vB0, vB1, vB2, vB3;
            int jA1, jA2, jA3, jB1, jB2, jB3;
            // --- issue all index loads ---
            if (mA) {
                jA1 = iA + 4; jA2 = iA + 8; jA3 = iA + 12;
                sA0 = srcs[(unsigned)iA];
                sA1 = srcs[(unsigned)((jA1 < endA) ? jA1 : eA1)];
                sA2 = srcs[(unsigned)((jA2 < endA) ? jA2 : eA1)];
                sA3 = srcs[(unsigned)((jA3 < endA) ? jA3 : eA1)];
            }
            if (mB) {
                jB1 = iB + 4; jB2 = iB + 8; jB3 = iB + 12;
                sB0 = srcs[(unsigned)iB];
                sB1 = srcs[(unsigned)((jB1 < endB) ? jB1 : eB1)];
                sB2 = srcs[(unsigned)((jB2 < endB) ? jB2 : eB1)];
                sB3 = srcs[(unsigned)((jB3 < endB) ? jB3 : eB1)];
            }
            // --- issue all gathers (8 in flight) ---
            if (mA) {
                vA0 = h1v[(unsigned)sA0 * 16u + uli];
                vA1 = h1v[(unsigned)sA1 * 16u + uli];
                vA2 = h1v[(unsigned)sA2 * 16u + uli];
                vA3 = h1v[(unsigned)sA3 * 16u + uli];
            }
            if (mB) {
                vB0 = h1v[(unsigned)sB0 * 16u + uli];
                vB1 = h1v[(unsigned)sB1 * 16u + uli];
                vB2 = h1v[(unsigned)sB2 * 16u + uli];
                vB3 = h1v[(unsigned)sB3 * 16u + uli];
            }
            // --- consume ---
            if (mA) {
                aA0 += bflo(vA0.x); aA1 += bfhi(vA0.x);
                aA2 += bflo(vA0.y); aA3 += bfhi(vA0.y);
                if (jA1 < endA) {
                    aA0 += bflo(vA1.x); aA1 += bfhi(vA1.x);
                    aA2 += bflo(vA1.y); aA3 += bfhi(vA1.y);
                }
                if (jA2 < endA) {
                    aA0 += bflo(vA2.x); aA1 += bfhi(vA2.x);
                    aA2 += bflo(vA2.y); aA3 += bfhi(vA2.y);
                }
                if (jA3 < endA) {
                    aA0 += bflo(vA3.x); aA1 += bfhi(vA3.x);
                    aA2 += bflo(vA3.y); aA3 += bfhi(vA3.y);
                }
                iA += 16; mA = iA < endA;
            }
            if (mB) {
                aB0 += bflo(vB0.x); aB1 += bfhi(vB0.x);
                aB2 += bflo(vB0.y); aB3 += bfhi(vB0.y);
                if (jB1 < endB) {
                    aB0 += bflo(vB1.x); aB1 += bfhi(vB1.x);
                    aB2 += bflo(vB1.y); aB3 += bfhi(vB1.y);
                }
                if (jB2 < endB) {
                    aB0 += bflo(vB2.x); aB1 += bfhi(vB2.x);
                    aB2 += bflo(vB2.y); aB3 += bfhi(vB2.y);
                }
                if (jB3 < endB) {
                    aB0 += bflo(vB3.x); aB1 += bfhi(vB3.x);
                    aB2 += bflo(vB3.y); aB3 += bfhi(vB3.y);
                }
                iB += 16; mB = iB < endB;
            }
        }

        // --- interleaved cross-slot reductions (A and B pipelined) ---
        aA0 += __shfl_xor(aA0, 16); aB0 += __shfl_xor(aB0, 16);
        aA1 += __shfl_xor(aA1, 16); aB1 += __shfl_xor(aB1, 16);
        aA2 += __shfl_xor(aA2, 16); aB2 += __shfl_xor(aB2, 16);
        aA3 += __shfl_xor(aA3, 16); aB3 += __shfl_xor(aB3, 16);
        aA0 += __shfl_xor(aA0, 32); aB0 += __shfl_xor(aB0, 32);
        aA1 += __shfl_xor(aA1, 32); aB1 += __shfl_xor(aB1, 32);
        aA2 += __shfl_xor(aA2, 32); aB2 += __shfl_xor(aB2, 32);
        aA3 += __shfl_xor(aA3, 32); aB3 += __shfl_xor(aB3, 32);

        const float tA0 = fmaxf(fmaf(aA0, ndA, bias0), 0.f);
        const float tA1 = fmaxf(fmaf(aA1, ndA, bias1), 0.f);
        const float tA2 = fmaxf(fmaf(aA2, ndA, bias2), 0.f);
        const float tA3 = fmaxf(fmaf(aA3, ndA, bias3), 0.f);
        const float tB0 = fmaxf(fmaf(aB0, ndB, bias0), 0.f);
        const float tB1 = fmaxf(fmaf(aB1, ndB, bias1), 0.f);
        const float tB2 = fmaxf(fmaf(aB2, ndB, bias2), 0.f);
        const float tB3 = fmaxf(fmaf(aB3, ndB, bias3), 0.f);

        float pA0 = fmaf(tA0,w2[0][0],fmaf(tA1,w2[1][0],fmaf(tA2,w2[2][0],tA3*w2[3][0])));
        float pA1 = fmaf(tA0,w2[0][1],fmaf(tA1,w2[1][1],fmaf(tA2,w2[2][1],tA3*w2[3][1])));
        float pA2 = fmaf(tA0,w2[0][2],fmaf(tA1,w2[1][2],fmaf(tA2,w2[2][2],tA3*w2[3][2])));
        float pA3 = fmaf(tA0,w2[0][3],fmaf(tA1,w2[1][3],fmaf(tA2,w2[2][3],tA3*w2[3][3])));
        float pB0 = fmaf(tB0,w2[0][0],fmaf(tB1,w2[1][0],fmaf(tB2,w2[2][0],tB3*w2[3][0])));
        float pB1 = fmaf(tB0,w2[0][1],fmaf(tB1,w2[1][1],fmaf(tB2,w2[2][1],tB3*w2[3][1])));
        float pB2 = fmaf(tB0,w2[0][2],fmaf(tB1,w2[1][2],fmaf(tB2,w2[2][2],tB3*w2[3][2])));
        float pB3 = fmaf(tB0,w2[0][3],fmaf(tB1,w2[1][3],fmaf(tB2,w2[2][3],tB3*w2[3][3])));
        #pragma unroll
        for (int off = 1; off <= 8; off <<= 1) {
            pA0 += __shfl_xor(pA0, off); pB0 += __shfl_xor(pB0, off);
            pA1 += __shfl_xor(pA1, off); pB1 += __shfl_xor(pB1, off);
            pA2 += __shfl_xor(pA2, off); pB2 += __shfl_xor(pB2, off);
            pA3 += __shfl_xor(pA3, off); pB3 += __shfl_xor(pB3, off);
        }
        if (li < 4) {
            float vA = (li == 0) ? pA0 : (li == 1) ? pA1 : (li == 2) ? pA2 : pA3;
            float vB = (li == 0) ? pB0 : (li == 1) ? pB1 : (li == 2) ? pB2 : pB3;
            h2[(size_t)rA * NC + q + 4*li] = f2us_rn(vA * nsA);
            h2[(size_t)rB * NC + q + 4*li] = f2us_rn(vB * nsB);
        }

        rA = nrA;
        begA = nbegA; endA = nendA; begB = nbegB; endB = nendB;
        ndA = nndA; nsA = nnsA; ndB = nndB; nsB = nnsB;
    }
}

// ---------------- fused layer-2 aggregation + bias + log_softmax ----------------
// R13: same two-row interleave as k_agg1csr (identical starvation signature).
__global__ __launch_bounds__(256) void k_out(
    const int* __restrict__ row_off, const int* __restrict__ srcs,
    const unsigned short* __restrict__ h2, const float* __restrict__ ndst,
    const void* __restrict__ b2, const int* __restrict__ mode,
    void* __restrict__ out)
{
    const bool f32 = (mode[0] != 0);
    const int lane = threadIdx.x & 63;
    const int q  = lane >> 3;
    const int li = lane & 7;
    const float b2v0 = ldf(b2, 2*li,   f32);
    const float b2v1 = ldf(b2, 2*li+1, f32);

    const int wid = (blockIdx.x * blockDim.x + threadIdx.x) >> 6;
    const int nw  = (gridDim.x * blockDim.x) >> 6;
    const unsigned* __restrict__ h2v = (const unsigned*)h2;
    const unsigned uli = (unsigned)li;

    int rA = wid;
    if (rA >= NHALF) return;
    int begA = row_off[rA],         endA = row_off[rA + 1];
    int begB = row_off[rA + NHALF], endB = row_off[rA + NHALF + 1];
    float ndA = ndst[rA], ndB = ndst[rA + NHALF];

    while (rA < NHALF) {
        const int rB = rA + NHALF;
        const int nrA = rA + nw;
        int nbegA = 0, nendA = 0, nbegB = 0, nendB = 0;
        float nndA = 0.f, nndB = 0.f;
        if (nrA < NHALF) {
            nbegA = row_off[nrA];         nendA = row_off[nrA + 1];
            nbegB = row_off[nrA + NHALF]; nendB = row_off[nrA + NHALF + 1];
            nndA = ndst[nrA];             nndB = ndst[nrA + NHALF];
        }

        float aA0 = 0.f, aA1 = 0.f, aB0 = 0.f, aB1 = 0.f;
        const int eA1 = endA - 1, eB1 = endB - 1;
        int iA = begA + q, iB = begB + q;
        bool mA = iA < endA, mB = iB < endB;
        while (mA || mB) {
            int sA0, sA1, sB0, sB1, jA1, jB1;
            unsigned uA0, uA1, uB0, uB1;
            if (mA) {
                jA1 = iA + 8;
                sA0 = srcs[(unsigned)iA];
                sA1 = srcs[(unsigned)((jA1 < endA) ? jA1 : eA1)];
            }
            if (mB) {
                jB1 = iB + 8;
                sB0 = srcs[(unsigned)iB];
                sB1 = srcs[(unsigned)((jB1 < endB) ? jB1 : eB1)];
            }
            if (mA) {
                uA0 = h2v[(unsigned)sA0 * 8u + uli];
                uA1 = h2v[(unsigned)sA1 * 8u + uli];
            }
            if (mB) {
                uB0 = h2v[(unsigned)sB0 * 8u + uli];
                uB1 = h2v[(unsigned)sB1 * 8u + uli];
            }
            if (mA) {
                aA0 += bflo(uA0); aA1 += bfhi(uA0);
                if (jA1 < endA) { aA0 += bflo(uA1); aA1 += bfhi(uA1); }
                iA += 16; mA = iA < endA;
            }
            if (mB) {
                aB0 += bflo(uB0); aB1 += bfhi(uB0);
                if (jB1 < endB) { aB0 += bflo(uB1); aB1 += bfhi(uB1); }
                iB += 16; mB = iB < endB;
            }
        }
        #pragma unroll
        for (int off = 8; off <= 32; off <<= 1) {
            aA0 += __shfl_xor(aA0, off); aB0 += __shfl_xor(aB0, off);
            aA1 += __shfl_xor(aA1, off); aB1 += __shfl_xor(aB1, off);
        }
        float vA0 = fmaf(aA0, ndA, b2v0);
        float vA1 = fmaf(aA1, ndA, b2v1);
        float vB0 = fmaf(aB0, ndB, b2v0);
        float vB1 = fmaf(aB1, ndB, b2v1);
        float mxA = fmaxf(vA0, vA1);
        float mxB = fmaxf(vB0, vB1);
        #pragma unroll
        for (int off = 1; off <= 4; off <<= 1) {
            mxA = fmaxf(mxA, __shfl_xor(mxA, off));
            mxB = fmaxf(mxB, __shfl_xor(mxB, off));
        }
        float smA = __expf(vA0 - mxA) + __expf(vA1 - mxA);
        float smB = __expf(vB0 - mxB) + __expf(vB1 - mxB);
        #pragma unroll
        for (int off = 1; off <= 4; off <<= 1) {
            smA += __shfl_xor(smA, off);
            smB += __shfl_xor(smB, off);
        }
        const float lsmA = __logf(smA), lsmB = __logf(smB);
        const float rA0 = vA0 - mxA - lsmA, rA1 = vA1 - mxA - lsmA;
        const float rB0 = vB0 - mxB - lsmB, rB1 = vB1 - mxB - lsmB;
        if (q == 0) {
            if (f32) {
                float2 oA; oA.x = rA0; oA.y = rA1;
                float2 oB; oB.x = rB0; oB.y = rB1;
                *(float2*)((float*)out + (size_t)rA * NC + 2*li) = oA;
                *(float2*)((float*)out + (size_t)rB * NC + 2*li) = oB;
            } else {
                unsigned oA = ((unsigned)f2us_rn(rA1) << 16) | (unsigned)f2us_rn(rA0);
                unsigned oB = ((unsigned)f2us_rn(rB1) << 16) | (unsigned)f2us_rn(rB0);
                *(unsigned*)((unsigned short*)out + (size_t)rA * NC + 2*li) = oA;
                *(unsigned*)((unsigned short*)out + (size_t)rB * NC + 2*li) = oB;
            }
        }

        rA = nrA;
        begA = nbegA; endA = nendA; begB = nbegB; endB = nendB;
        ndA = nndA; ndB = nndB;
    }
}

extern "C" void kernel_launch(void* const* d_in, const int* in_sizes, int n_in,
                              void* d_out, int out_size, void* d_ws, size_t ws_size,
                              hipStream_t stream) {
    const void* x  = d_in[0];
    const int* src = (const int*)d_in[1];
    const int* dst = (const int*)d_in[2];
    const void* W1 = d_in[3];
    const void* b1 = d_in[4];
    const void* W2 = d_in[5];
    const void* b2 = d_in[6];

    // ---- workspace layout ----
    char* ws = (char*)d_ws;
    const size_t O_MODE = 0;                     // 1 KB
    const size_t O_W1F  = 1024;                  // fragment-ordered W1 (bf16), 16384 B
    const size_t O_CNT  = O_W1F + 16384;         // counts_d + counts_s = 401408
    const size_t O_CS   = O_CNT  + 401408;       // csum 2048 + coff 2048
    const size_t O_DEG  = O_CS   + 4096;         // 800000 (fallback only)
    const size_t O_NSRC = O_DEG  + 800000;
    const size_t O_NDST = O_NSRC + 400000;
    const size_t O_ROW  = O_NDST + 400000;       // (NN+1)*4 padded
    const size_t O_CUR  = O_ROW  + 400128;       // fallback per-node cursors
    const size_t O_BS   = O_CUR  + 400128;       // bsum 2048 + boff 2048 (fallback)
    const size_t O_SRCS = O_BS   + 4096;         // NE*4
    const size_t O_H2   = O_SRCS + 6400000;      // NN*NC*2 bf16
    const size_t O_H1   = O_H2   + 3200000;      // NN*NH*2 bf16 = 12800000
    // packed (NE*4) + packed2 (NE*2) alias into h1 (dead before gemm1)
    const size_t NEED = O_H1 + 12800000;         // ~25.2 MB
    const bool fast_csr = ws_size >= NEED;

    int*   mode     = (int*)(ws + O_MODE);
    unsigned short* W1f = (unsigned short*)(ws + O_W1F);
    int*   counts_d = (int*)(ws + O_CNT);
    int*   counts_s = counts_d + BBUK * GBIN;
    int*   csum     = (int*)(ws + O_CS);
    int*   coff     = (int*)(ws + O_CS + 2048);
    int*   deg_out  = (int*)(ws + O_DEG);
    int*   deg_in   = deg_out + NN;
    float* nsrc     = (float*)(ws + O_NSRC);
    float* ndst     = (float*)(ws + O_NDST);
    int*   row_off  = (int*)(ws + O_ROW);
    int*   cursor   = (int*)(ws + O_CUR);
    int*   bsum     = (int*)(ws + O_BS);
    int*   boff     = (int*)(ws + O_BS + 2048);
    int*   srcs_s   = (int*)(ws + O_SRCS);
    unsigned short* h2 = (unsigned short*)(ws + O_H2);
    unsigned short* h1 = (unsigned short*)(ws + O_H1);
    unsigned int*   packed  = (unsigned int*)(ws + O_H1);
    unsigned short* packed2 = (unsigned short*)(ws + O_H1 + 6400000);

    k_sniff<<<1, 256, 0, stream>>>((const unsigned short*)x, mode);
    k_prepW<<<1, 256, 0, stream>>>(W1, W1f, mode);
    if (fast_csr) {
        k_hist2<<<GBIN, 256, 0, stream>>>(src, dst, counts_d, counts_s);
        k_cs_a<<<2 * NCB, 256, 0, stream>>>(counts_d, csum);
        k_cs_b2<<<1, 512, 0, stream>>>(csum, coff);
        k_cs_c<<<2 * NCB, 256, 0, stream>>>(counts_d, coff);
        k_binscatter2<<<GBIN, 256, 0, stream>>>(src, dst, counts_d, counts_s, packed, packed2);
        k_bdeg_out_nsrc<<<BBUK, 256, 0, stream>>>(counts_s, packed2, nsrc);
        k_bucket_all<<<BBUK, 256, 0, stream>>>(counts_d, packed, row_off, ndst, srcs_s);
    } else {
        hipMemsetAsync(deg_out, 0, 2 * (size_t)NN * sizeof(int), stream);
        k_deg<<<(NE / 4 + 255) / 256, 256, 0, stream>>>((const int4*)src, (const int4*)dst, deg_out, deg_in);
        k_scan_a<<<NB1, 256, 0, stream>>>(deg_in, bsum);
        k_scan_b<<<1, 512, 0, stream>>>(bsum, boff);
        k_scan_c<<<NB1, 256, 0, stream>>>(deg_in, deg_out, boff, row_off, cursor, nsrc, ndst);
        k_scatter<<<(NE + 255) / 256, 256, 0, stream>>>(src, dst, cursor, srcs_s);
    }
    k_gemm1_mfma<<<NGRP, 256, 0, stream>>>(x, W1f, nsrc, h1, mode);
    k_agg1csr<<<2048, 256, 0, stream>>>(row_off, srcs_s, h1, ndst, nsrc, b1, W2, mode, h2);
    k_out<<<2048, 256, 0, stream>>>(row_off, srcs_s, h2, ndst, b2, mode, d_out);
}